// Round 6
// baseline (195.081 us; speedup 1.0000x reference)
//
#include <hip/hip_runtime.h>

#define BETA2 25.0f
#define EPS 1e-9f
#define BLOCK 256
#define GRID 2048
#define UN 4
#define CHUNK (BLOCK * UN)   // float4s consumed per array per block per iteration

// d_ws layout: [0..3] uint done-counter | pad to 64 B | uint partials[3][GRID]
// Counter is zeroed via hipMemsetAsync each call (d_ws is poisoned, not re-poisoned).

__device__ __forceinline__ void acc3(float t, float l, int& tp, int& fp, int& fn) {
    int tn = (t != 0.0f), ln = (l != 0.0f);
    tp += tn & ln;
    fp += tn & (ln ^ 1);
    fn += (tn ^ 1) & ln;
}

__global__ void __launch_bounds__(BLOCK) fbeta_fused(const float4* __restrict__ t4,
                                                     const float4* __restrict__ l4,
                                                     unsigned int* __restrict__ ws,
                                                     float* __restrict__ out,
                                                     int n4) {
    unsigned int* counter  = ws;
    unsigned int* partials = ws + 16;   // byte offset 64

    int tp = 0, fp = 0, fn = 0;
    const int nchunks = n4 / CHUNK;     // 8192 at N=2^26 (exact)

    // --- streaming phase: byte-identical to R4's loop ---
    for (int c = blockIdx.x; c < nchunks; c += gridDim.x) {
        const int base = c * CHUNK + threadIdx.x;
        float4 tv[UN], lv[UN];
        #pragma unroll
        for (int k = 0; k < UN; ++k) tv[k] = t4[base + k * BLOCK];
        #pragma unroll
        for (int k = 0; k < UN; ++k) lv[k] = l4[base + k * BLOCK];
        #pragma unroll
        for (int k = 0; k < UN; ++k) {
            acc3(tv[k].x, lv[k].x, tp, fp, fn);
            acc3(tv[k].y, lv[k].y, tp, fp, fn);
            acc3(tv[k].z, lv[k].z, tp, fp, fn);
            acc3(tv[k].w, lv[k].w, tp, fp, fn);
        }
    }
    for (int i = nchunks * CHUNK + blockIdx.x * BLOCK + threadIdx.x; i < n4;
         i += gridDim.x * BLOCK) {
        float4 tv = t4[i];
        float4 lv = l4[i];
        acc3(tv.x, lv.x, tp, fp, fn);
        acc3(tv.y, lv.y, tp, fp, fn);
        acc3(tv.z, lv.z, tp, fp, fn);
        acc3(tv.w, lv.w, tp, fp, fn);
    }

    // wave-64 reduction
    #pragma unroll
    for (int off = 32; off > 0; off >>= 1) {
        tp += __shfl_down(tp, off, 64);
        fp += __shfl_down(fp, off, 64);
        fn += __shfl_down(fn, off, 64);
    }

    __shared__ int s[3][BLOCK / 64];
    __shared__ int lastFlag;
    const int wave = threadIdx.x >> 6;
    if ((threadIdx.x & 63) == 0) {
        s[0][wave] = tp;
        s[1][wave] = fp;
        s[2][wave] = fn;
    }
    __syncthreads();

    if (threadIdx.x == 0) {
        int btp = 0, bfp = 0, bfn = 0;
        #pragma unroll
        for (int w = 0; w < BLOCK / 64; ++w) {
            btp += s[0][w];
            bfp += s[1][w];
            bfn += s[2][w];
        }
        partials[blockIdx.x]            = (unsigned int)btp;
        partials[GRID + blockIdx.x]     = (unsigned int)bfp;
        partials[2 * GRID + blockIdx.x] = (unsigned int)bfn;
        __threadfence();                               // release: partials visible device-wide
        unsigned int old = atomicAdd(counter, 1u);     // device-scope
        lastFlag = (old == gridDim.x - 1);
    }
    __syncthreads();
    if (!lastFlag) return;

    // --- last block: final reduction (agent-scope loads bypass stale L1) ---
    __threadfence();                                   // acquire side
    unsigned int ftp = 0, ffp = 0, ffn = 0;
    for (int b = threadIdx.x; b < GRID; b += BLOCK) {
        ftp += __hip_atomic_load(&partials[b],            __ATOMIC_RELAXED, __HIP_MEMORY_SCOPE_AGENT);
        ffp += __hip_atomic_load(&partials[GRID + b],     __ATOMIC_RELAXED, __HIP_MEMORY_SCOPE_AGENT);
        ffn += __hip_atomic_load(&partials[2 * GRID + b], __ATOMIC_RELAXED, __HIP_MEMORY_SCOPE_AGENT);
    }
    #pragma unroll
    for (int off = 32; off > 0; off >>= 1) {
        ftp += __shfl_down(ftp, off, 64);
        ffp += __shfl_down(ffp, off, 64);
        ffn += __shfl_down(ffn, off, 64);
    }
    if ((threadIdx.x & 63) == 0) {
        s[0][wave] = (int)ftp;
        s[1][wave] = (int)ffp;
        s[2][wave] = (int)ffn;
    }
    __syncthreads();
    if (threadIdx.x == 0) {
        float rtp = 0.f, rfp = 0.f, rfn = 0.f;
        #pragma unroll
        for (int w = 0; w < BLOCK / 64; ++w) {
            rtp += (float)s[0][w];
            rfp += (float)s[1][w];
            rfn += (float)s[2][w];
        }
        rtp += EPS; rfp += EPS; rfn += EPS;
        float precision = rtp / (rtp + rfp);
        float recall    = rtp / (rtp + rfn);
        out[0] = (1.0f + BETA2) * (precision * recall) / (BETA2 * precision + recall);
    }
}

extern "C" void kernel_launch(void* const* d_in, const int* in_sizes, int n_in,
                              void* d_out, int out_size, void* d_ws, size_t ws_size,
                              hipStream_t stream) {
    const float* targets = (const float*)d_in[0];
    const float* labels  = (const float*)d_in[1];
    float* out = (float*)d_out;
    unsigned int* ws = (unsigned int*)d_ws;

    const int n = in_sizes[0];      // 67108864
    const int n4 = n >> 2;          // 16777216 float4s

    // Zero the done-counter (d_ws is poisoned once and never re-poisoned).
    hipMemsetAsync(d_ws, 0, 64, stream);

    fbeta_fused<<<GRID, BLOCK, 0, stream>>>((const float4*)targets,
                                            (const float4*)labels,
                                            ws, out, n4);
}

// Round 7
// 94.220 us; speedup vs baseline: 2.0705x; 2.0705x over previous
//
#include <hip/hip_runtime.h>

#define BETA2 25.0f
#define EPS 1e-9f
#define BLOCK 256
#define GRID 2048
#define UN 4
#define CHUNK (BLOCK * UN)   // float4s consumed per array per block per iteration

// d_ws layout (SoA, uint): [GRID] tp | [GRID] fp | [GRID] fn  (GRID multiple of 4 -> uint4 ok)

__device__ __forceinline__ void acc3(float t, float l, int& tp, int& fp, int& fn) {
    int tn = (t != 0.0f), ln = (l != 0.0f);
    tp += tn & ln;
    fp += tn & (ln ^ 1);
    fn += (tn ^ 1) & ln;
}

__global__ void __launch_bounds__(BLOCK) fbeta_count(const float4* __restrict__ t4,
                                                     const float4* __restrict__ l4,
                                                     unsigned int* __restrict__ partials,
                                                     int n4, int nblocks) {
    int tp = 0, fp = 0, fn = 0;
    const int nchunks = n4 / CHUNK;          // 16384 at N=2^26 (exact)

    for (int c = blockIdx.x; c < nchunks; c += gridDim.x) {
        const int base = c * CHUNK + threadIdx.x;
        float4 tv[UN], lv[UN];
        #pragma unroll
        for (int k = 0; k < UN; ++k) tv[k] = t4[base + k * BLOCK];
        #pragma unroll
        for (int k = 0; k < UN; ++k) lv[k] = l4[base + k * BLOCK];
        #pragma unroll
        for (int k = 0; k < UN; ++k) {
            acc3(tv[k].x, lv[k].x, tp, fp, fn);
            acc3(tv[k].y, lv[k].y, tp, fp, fn);
            acc3(tv[k].z, lv[k].z, tp, fp, fn);
            acc3(tv[k].w, lv[k].w, tp, fp, fn);
        }
    }

    // Tail (not hit at N=2^26).
    for (int i = nchunks * CHUNK + blockIdx.x * BLOCK + threadIdx.x; i < n4;
         i += gridDim.x * BLOCK) {
        float4 tv = t4[i];
        float4 lv = l4[i];
        acc3(tv.x, lv.x, tp, fp, fn);
        acc3(tv.y, lv.y, tp, fp, fn);
        acc3(tv.z, lv.z, tp, fp, fn);
        acc3(tv.w, lv.w, tp, fp, fn);
    }

    // wave-64 reduction
    #pragma unroll
    for (int off = 32; off > 0; off >>= 1) {
        tp += __shfl_down(tp, off, 64);
        fp += __shfl_down(fp, off, 64);
        fn += __shfl_down(fn, off, 64);
    }

    // cross-wave reduction in LDS, plain per-block stores (no atomics, no fences)
    __shared__ int s[3][BLOCK / 64];
    const int wave = threadIdx.x >> 6;
    if ((threadIdx.x & 63) == 0) {
        s[0][wave] = tp;
        s[1][wave] = fp;
        s[2][wave] = fn;
    }
    __syncthreads();
    if (threadIdx.x == 0) {
        int btp = 0, bfp = 0, bfn = 0;
        #pragma unroll
        for (int w = 0; w < BLOCK / 64; ++w) {
            btp += s[0][w];
            bfp += s[1][w];
            bfn += s[2][w];
        }
        partials[blockIdx.x]               = (unsigned int)btp;
        partials[nblocks + blockIdx.x]     = (unsigned int)bfp;
        partials[2 * nblocks + blockIdx.x] = (unsigned int)bfn;
    }
}

__global__ void __launch_bounds__(BLOCK) fbeta_reduce(const uint4* __restrict__ p4,
                                                      float* __restrict__ out, int nblocks) {
    // partials viewed as uint4: [GRID/4] tp | [GRID/4] fp | [GRID/4] fn
    const int q = nblocks / 4;               // 512
    unsigned int tp = 0, fp = 0, fn = 0;
    for (int b = threadIdx.x; b < q; b += BLOCK) {
        uint4 a = p4[b];
        uint4 c = p4[q + b];
        uint4 d = p4[2 * q + b];
        tp += a.x + a.y + a.z + a.w;
        fp += c.x + c.y + c.z + c.w;
        fn += d.x + d.y + d.z + d.w;
    }
    #pragma unroll
    for (int off = 32; off > 0; off >>= 1) {
        tp += __shfl_down(tp, off, 64);
        fp += __shfl_down(fp, off, 64);
        fn += __shfl_down(fn, off, 64);
    }
    __shared__ unsigned int s[3][BLOCK / 64];
    const int wave = threadIdx.x >> 6;
    if ((threadIdx.x & 63) == 0) {
        s[0][wave] = tp;
        s[1][wave] = fp;
        s[2][wave] = fn;
    }
    __syncthreads();
    if (threadIdx.x == 0) {
        float ftp = 0.f, ffp = 0.f, ffn = 0.f;
        #pragma unroll
        for (int w = 0; w < BLOCK / 64; ++w) {
            ftp += (float)s[0][w];
            ffp += (float)s[1][w];
            ffn += (float)s[2][w];
        }
        ftp += EPS; ffp += EPS; ffn += EPS;
        float precision = ftp / (ftp + ffp);
        float recall    = ftp / (ftp + ffn);
        out[0] = (1.0f + BETA2) * (precision * recall) / (BETA2 * precision + recall);
    }
}

extern "C" void kernel_launch(void* const* d_in, const int* in_sizes, int n_in,
                              void* d_out, int out_size, void* d_ws, size_t ws_size,
                              hipStream_t stream) {
    const float* targets = (const float*)d_in[0];
    const float* labels  = (const float*)d_in[1];
    float* out = (float*)d_out;
    unsigned int* partials = (unsigned int*)d_ws;

    const int n = in_sizes[0];      // 67108864
    const int n4 = n >> 2;          // 16777216 float4s

    fbeta_count<<<GRID, BLOCK, 0, stream>>>((const float4*)targets,
                                            (const float4*)labels,
                                            partials, n4, GRID);
    fbeta_reduce<<<1, BLOCK, 0, stream>>>((const uint4*)partials, out, GRID);
}